// Round 11
// baseline (242.683 us; speedup 1.0000x reference)
//
#include <hip/hip_runtime.h>
#include <hip/hip_bf16.h>
#include <math.h>

#define BB   2
#define MM   2048      // l*n
#define DIM  512
#define NH   8
#define DHd  64
#define NQK  1536
#define ROWS 4096      // BB*MM
#define NROW 32768     // 16 bh * 2048 rows

typedef __hip_bfloat16 bf16;
typedef __attribute__((ext_vector_type(8))) short bf16x8;
typedef __attribute__((ext_vector_type(4))) float f32x4;
typedef __attribute__((ext_vector_type(8))) unsigned short us8;

__device__ __forceinline__ unsigned short f2bf_bits(float x) {
    bf16 h = __float2bfloat16(x);
    return *(unsigned short*)&h;
}
__device__ __forceinline__ float bf2f(unsigned short u) {
    unsigned int v = ((unsigned int)u) << 16;
    return __uint_as_float(v);
}

// ---- fused pre-pass: LayerNorm + weight transposes + xyz transpose --------
__global__ __launch_bounds__(256) void pre_kernel(
    const float* __restrict__ feat, const float* __restrict__ gamma,
    const float* __restrict__ beta, unsigned short* __restrict__ normed,
    const float* __restrict__ wqkv, const float* __restrict__ wout,
    unsigned short* __restrict__ wqkvT, unsigned short* __restrict__ woutT,
    const float* __restrict__ xyzs, unsigned short* __restrict__ xyzT)
{
    __shared__ float st[64][65];
    int b = blockIdx.x;
    int tid = threadIdx.x;
    if (b < ROWS) {
        const float* fr = feat + (size_t)b * DIM;
        float x0 = fr[tid];
        float x1 = fr[tid + 256];
        float s  = x0 + x1;
        float ss = x0 * x0 + x1 * x1;
        #pragma unroll
        for (int o = 32; o >= 1; o >>= 1) { s += __shfl_down(s, o); ss += __shfl_down(ss, o); }
        __shared__ float ws_[4], wss_[4];
        int wid = tid >> 6, lane = tid & 63;
        if (lane == 0) { ws_[wid] = s; wss_[wid] = ss; }
        __syncthreads();
        if (tid == 0) {
            float a = 0.f, c = 0.f;
            for (int i = 0; i < 4; i++) { a += ws_[i]; c += wss_[i]; }
            ws_[0] = a; wss_[0] = c;
        }
        __syncthreads();
        float mu  = ws_[0] * (1.0f / DIM);
        float var = wss_[0] * (1.0f / DIM) - mu * mu;
        float inv = rsqrtf(var + 1e-5f);
        normed[(size_t)b * DIM + tid]       = f2bf_bits((x0 - mu) * inv * gamma[tid] + beta[tid]);
        normed[(size_t)b * DIM + tid + 256] = f2bf_bits((x1 - mu) * inv * gamma[tid + 256] + beta[tid + 256]);
        return;
    }
    if (b == ROWS + 256) {
        // xyzT[b][c][m] = bf16(xyzs[b][m][c])
        for (int e = tid; e < BB * 3 * MM; e += 256) {
            int b_ = e / (3 * MM);
            int rem = e - b_ * 3 * MM;
            int c = rem / MM, m = rem - c * MM;
            xyzT[e] = f2bf_bits(xyzs[((size_t)b_ * MM + m) * 3 + c]);
        }
        return;
    }
    int idx = b - ROWS;
    const float* in; unsigned short* out; int N, n0;
    if (idx < 192) { in = wqkv; out = wqkvT; N = NQK; n0 = (idx >> 3) * 64; }
    else { idx -= 192; in = wout; out = woutT; N = DIM; n0 = (idx >> 3) * 64; }
    int k0 = (idx & 7) * 64;
    #pragma unroll
    for (int p = 0; p < 16; p++) {
        int e = tid + p * 256;
        int r = e >> 6, c = e & 63;
        st[r][c] = in[(size_t)(k0 + r) * N + n0 + c];
    }
    __syncthreads();
    #pragma unroll
    for (int p = 0; p < 16; p++) {
        int e = tid + p * 256;
        int nr = e >> 6, kc = e & 63;
        out[(size_t)(n0 + nr) * DIM + k0 + kc] = f2bf_bits(st[kc][nr]);
    }
}

// ---- QKV GEMM (MFMA): q/k blocks computed transposed (A=weights) so the
//      accumulator's reg axis lands on d -> ushort4 stores. q scaled by
//      (1/8)*log2(e) so attention can use exp2.
__global__ __launch_bounds__(256) void qkv_gemm(
    const unsigned short* __restrict__ A, const unsigned short* __restrict__ BT,
    unsigned short* __restrict__ qd, unsigned short* __restrict__ kd,
    unsigned short* __restrict__ vd)
{
    __shared__ __align__(16) unsigned short sA[128 * 40];
    __shared__ __align__(16) unsigned short sB[128 * 40];
    int tid = threadIdx.x;
    int r0 = blockIdx.x * 128;
    int n0 = blockIdx.y * 128;
    int chunk = n0 >> 9;           // 0=q 1=k 2=v
    int cl    = n0 & 511;
    int w = tid >> 6, lane = tid & 63;
    int wm = w >> 1, wn = w & 1;
    int ln15 = lane & 15, quad = lane >> 4;

    int srow = tid >> 1;
    int scol = (tid & 1) * 16;

    f32x4 acc[4][4] = {};

    for (int k0 = 0; k0 < DIM; k0 += 32) {
        __syncthreads();
        *(us8*)&sA[srow * 40 + scol]     = *(const us8*)&A[(size_t)(r0 + srow) * DIM + k0 + scol];
        *(us8*)&sA[srow * 40 + scol + 8] = *(const us8*)&A[(size_t)(r0 + srow) * DIM + k0 + scol + 8];
        *(us8*)&sB[srow * 40 + scol]     = *(const us8*)&BT[(size_t)(n0 + srow) * DIM + k0 + scol];
        *(us8*)&sB[srow * 40 + scol + 8] = *(const us8*)&BT[(size_t)(n0 + srow) * DIM + k0 + scol + 8];
        __syncthreads();
        const unsigned short* fa = (chunk == 2) ? sA : sB;
        const unsigned short* fb = (chunk == 2) ? sB : sA;
        bf16x8 af[4], bf_[4];
        #pragma unroll
        for (int i = 0; i < 4; i++)
            af[i] = *(const bf16x8*)&fa[(wm * 64 + i * 16 + ln15) * 40 + quad * 8];
        #pragma unroll
        for (int j = 0; j < 4; j++)
            bf_[j] = *(const bf16x8*)&fb[(wn * 64 + j * 16 + ln15) * 40 + quad * 8];
        #pragma unroll
        for (int i = 0; i < 4; i++)
            #pragma unroll
            for (int j = 0; j < 4; j++)
                acc[i][j] = __builtin_amdgcn_mfma_f32_16x16x32_bf16(af[i], bf_[j], acc[i][j], 0, 0, 0);
    }

    if (chunk == 2) {
        int rowb = r0 + wm * 64 + quad * 4;
        #pragma unroll
        for (int j = 0; j < 4; j++) {
            int c = cl + wn * 64 + j * 16 + ln15;
            int h = c >> 6, d = c & 63;
            #pragma unroll
            for (int i = 0; i < 4; i++) {
                int gr = rowb + i * 16;
                int bb = gr >> 11, mm = gr & 2047;
                ushort4 pk;
                pk.x = f2bf_bits(acc[i][j][0]);
                pk.y = f2bf_bits(acc[i][j][1]);
                pk.z = f2bf_bits(acc[i][j][2]);
                pk.w = f2bf_bits(acc[i][j][3]);
                *(ushort4*)&vd[((size_t)(bb * NH + h) * DHd + d) * MM + mm] = pk;
            }
        }
    } else {
        unsigned short* dst = (chunk == 0) ? qd : kd;
        float sc = (chunk == 0) ? 0.125f * 1.44269504f : 1.0f;
        #pragma unroll
        for (int i = 0; i < 4; i++) {
            int within0 = cl + wm * 64 + i * 16 + quad * 4;
            int h = within0 >> 6, d = within0 & 63;
            #pragma unroll
            for (int j = 0; j < 4; j++) {
                int gr = r0 + wn * 64 + j * 16 + ln15;
                int bb = gr >> 11, mm = gr & 2047;
                ushort4 pk;
                pk.x = f2bf_bits(acc[i][j][0] * sc);
                pk.y = f2bf_bits(acc[i][j][1] * sc);
                pk.z = f2bf_bits(acc[i][j][2] * sc);
                pk.w = f2bf_bits(acc[i][j][3] * sc);
                *(ushort4*)&dst[((size_t)(bb * NH + h) * MM + mm) * DHd + d] = pk;
            }
        }
    }
}

// ---------------- MFMA flash attention, split-K(2), BARRIER-FREE -----------
// All K/V/Q/xyz fragments load directly from global (16B/lane contiguous);
// only the P C->A layout round-trip uses LDS (wave-private, lgkmcnt only).
// No online max (S bounded); P = exp2(S*log2e) with log2e folded into q.
// V extended: cols 64..66 = key xyz, col 67 = 1 (gives l), 68..79 = 0.
__global__ __launch_bounds__(256, 4) void attn_kernel(
    const unsigned short* __restrict__ qg, const unsigned short* __restrict__ kg,
    const unsigned short* __restrict__ vg, const unsigned short* __restrict__ xyzT,
    unsigned short* __restrict__ obuf, float* __restrict__ lbuf)
{
    __shared__ __align__(16) unsigned short sP[64 * 72];

    int tid = threadIdx.x;
    int bh = blockIdx.y; int bb = bh >> 3;
    int i0 = blockIdx.x * 64;
    int ks = blockIdx.z;
    int w = tid >> 6;
    int lane = tid & 63;
    int ln15 = lane & 15;
    int quad = lane >> 4;

    // Q fragments straight from global (wave-owned rows)
    const unsigned short* qrow = qg + ((size_t)bh * MM + i0 + w * 16 + ln15) * DHd;
    bf16x8 aq0 = *(const bf16x8*)&qrow[quad * 8];
    bf16x8 aq1 = *(const bf16x8*)&qrow[32 + quad * 8];

    f32x4 o[5] = {};   // t=0..3: V cols; t=4: [x,y,z,l] at ln15=0..3

    const unsigned short* kbase = kg + (size_t)bh * MM * DHd;
    const unsigned short* vbase = vg + (size_t)bh * DHd * MM;
    const unsigned short* xbase = xyzT + (size_t)bb * 3 * MM;
    int jbeg = ks * (MM / 2), jend = jbeg + (MM / 2);

    int pwb = quad << 4;                       // write-side swizzle for sP
    int swzr = (ln15 >> 2) << 4;               // read-side swizzle
    int pr0 = (quad * 8) ^ swzr;
    int pr1 = (32 + quad * 8) ^ swzr;

    // constant ext fragments for ln15 >= 3
    us8 ones, zero;
    #pragma unroll
    for (int e = 0; e < 8; e++) { ones[e] = 0x3F80; zero[e] = 0; }

    for (int jt = jbeg; jt < jend; jt += 64) {
        // ---- K fragments (global), QK^T
        f32x4 sacc[4];
        #pragma unroll
        for (int t = 0; t < 4; t++) {
            const unsigned short* kr = &kbase[(size_t)(jt + t * 16 + ln15) * DHd + quad * 8];
            bf16x8 bk0 = *(const bf16x8*)kr;
            bf16x8 bk1 = *(const bf16x8*)(kr + 32);
            f32x4 z = {};
            z = __builtin_amdgcn_mfma_f32_16x16x32_bf16(aq0, bk0, z, 0, 0, 0);
            z = __builtin_amdgcn_mfma_f32_16x16x32_bf16(aq1, bk1, z, 0, 0, 0);
            sacc[t] = z;
        }
        // ---- V fragments (global) — issued early, consumed after P
        bf16x8 bv[5][2];
        #pragma unroll
        for (int t = 0; t < 4; t++) {
            const unsigned short* vr = &vbase[(size_t)(t * 16 + ln15) * MM + jt + quad * 8];
            bv[t][0] = *(const bf16x8*)vr;
            bv[t][1] = *(const bf16x8*)(vr + 32);
        }
        if (ln15 < 3) {
            const unsigned short* xr = &xbase[(size_t)ln15 * MM + jt + quad * 8];
            bv[4][0] = *(const bf16x8*)xr;
            bv[4][1] = *(const bf16x8*)(xr + 32);
        } else if (ln15 == 3) {
            bv[4][0] = *(bf16x8*)&ones; bv[4][1] = *(bf16x8*)&ones;
        } else {
            bv[4][0] = *(bf16x8*)&zero; bv[4][1] = *(bf16x8*)&zero;
        }

        // ---- P = 2^S, pack bf16, wave-private swizzled LDS round-trip
        #pragma unroll
        for (int t = 0; t < 4; t++) {
            int colb = (t * 16) ^ pwb;
            #pragma unroll
            for (int reg = 0; reg < 4; reg++) {
                float pv = exp2f(sacc[t][reg]);
                sP[(w * 16 + quad * 4 + reg) * 72 + colb + ln15] = f2bf_bits(pv);
            }
        }
        asm volatile("s_waitcnt lgkmcnt(0)" ::: "memory");
        bf16x8 ap0 = *(const bf16x8*)&sP[(w * 16 + ln15) * 72 + pr0];
        bf16x8 ap1 = *(const bf16x8*)&sP[(w * 16 + ln15) * 72 + pr1];
        #pragma unroll
        for (int t = 0; t < 5; t++) {
            o[t] = __builtin_amdgcn_mfma_f32_16x16x32_bf16(ap0, bv[t][0], o[t], 0, 0, 0);
            o[t] = __builtin_amdgcn_mfma_f32_16x16x32_bf16(ap1, bv[t][1], o[t], 0, 0, 0);
        }
    }

    // ---- store partials (unnormalized O and l; merge just sums)
    size_t kso = (size_t)ks * NROW;
    #pragma unroll
    for (int reg = 0; reg < 4; reg++) {
        size_t row = (size_t)bh * MM + i0 + w * 16 + quad * 4 + reg;
        unsigned short* orow = obuf + (kso + row) * 72;
        #pragma unroll
        for (int t = 0; t < 4; t++)
            orow[t * 16 + ln15] = f2bf_bits(o[t][reg]);
        if (ln15 < 3)  orow[64 + ln15] = f2bf_bits(o[4][reg]);   // xyz agg
        if (ln15 == 3) lbuf[kso + row] = o[4][reg];              // l (fp32)
    }
}

// ---------------- merge 2 split-K partials + w_sp epilogue -> bf16 ---------
__global__ __launch_bounds__(256) void merge_kernel(
    const unsigned short* __restrict__ obuf, const float* __restrict__ lbuf,
    const float* __restrict__ xyzs, const float* __restrict__ wsp,
    unsigned short* __restrict__ attn_out)
{
    __shared__ float sW[3][64];
    int tid = threadIdx.x;
    if (tid < 192) sW[tid >> 6][tid & 63] = wsp[tid];
    __syncthreads();
    int r   = blockIdx.x * 64 + (tid >> 2);
    int d0  = (tid & 3) * 16;
    int bh = r >> 11, qrow = r & 2047, bb = bh >> 3, hh = bh & 7;
    const unsigned short* p1 = obuf + (size_t)r * 72;
    const unsigned short* p2 = obuf + ((size_t)NROW + r) * 72;
    float invl = 1.f / (lbuf[r] + lbuf[NROW + r]);
    size_t xb = ((size_t)bb * MM + qrow) * 3;
    float gx = (bf2f(p1[64]) + bf2f(p2[64])) * invl - xyzs[xb + 0];
    float gy = (bf2f(p1[65]) + bf2f(p2[65])) * invl - xyzs[xb + 1];
    float gz = (bf2f(p1[66]) + bf2f(p2[66])) * invl - xyzs[xb + 2];
    us8 a0 = *(const us8*)&p1[d0];
    us8 a1 = *(const us8*)&p1[d0 + 8];
    us8 b0 = *(const us8*)&p2[d0];
    us8 b1 = *(const us8*)&p2[d0 + 8];
    unsigned short outv[16];
    #pragma unroll
    for (int e = 0; e < 8; e++) {
        int d = d0 + e;
        float v = (bf2f(a0[e]) + bf2f(b0[e])) * invl
                + gx * sW[0][d] + gy * sW[1][d] + gz * sW[2][d];
        outv[e] = f2bf_bits(v);
    }
    #pragma unroll
    for (int e = 0; e < 8; e++) {
        int d = d0 + 8 + e;
        float v = (bf2f(a1[e]) + bf2f(b1[e])) * invl
                + gx * sW[0][d] + gy * sW[1][d] + gz * sW[2][d];
        outv[8 + e] = f2bf_bits(v);
    }
    unsigned short* dst = attn_out + ((size_t)bb * MM + qrow) * DIM + hh * DHd + d0;
    *(us8*)dst       = *(us8*)&outv[0];
    *(us8*)(dst + 8) = *(us8*)&outv[8];
}

// ---- out GEMM (MFMA, 64x64 tiles): bf16 A @ bf16 BT^T + bias+GeLU+residual
__global__ __launch_bounds__(256) void out_gemm(
    const unsigned short* __restrict__ A, const unsigned short* __restrict__ BT,
    const float* __restrict__ bias, const float* __restrict__ feat,
    float* __restrict__ out)
{
    __shared__ __align__(16) unsigned short sA[64 * 40];
    __shared__ __align__(16) unsigned short sB[64 * 40];
    int tid = threadIdx.x;
    int r0 = blockIdx.x * 64, n0 = blockIdx.y * 64;
    int w = tid >> 6, lane = tid & 63;
    int wm = w >> 1, wn = w & 1;
    int ln15 = lane & 15, quad = lane >> 4;

    int srow = tid >> 2, scol = (tid & 3) * 8;

    f32x4 acc[2][2] = {};

    for (int k0 = 0; k0 < DIM; k0 += 32) {
        __syncthreads();
        *(us8*)&sA[srow * 40 + scol] = *(const us8*)&A[(size_t)(r0 + srow) * DIM + k0 + scol];
        *(us8*)&sB[srow * 40 + scol] = *(const us8*)&BT[(size_t)(n0 + srow) * DIM + k0 + scol];
        __syncthreads();
        bf16x8 af[2], bf_[2];
        #pragma unroll
        for (int i = 0; i < 2; i++)
            af[i] = *(const bf16x8*)&sA[(wm * 32 + i * 16 + ln15) * 40 + quad * 8];
        #pragma unroll
        for (int j = 0; j < 2; j++)
            bf_[j] = *(const bf16x8*)&sB[(wn * 32 + j * 16 + ln15) * 40 + quad * 8];
        #pragma unroll
        for (int i = 0; i < 2; i++)
            #pragma unroll
            for (int j = 0; j < 2; j++)
                acc[i][j] = __builtin_amdgcn_mfma_f32_16x16x32_bf16(af[i], bf_[j], acc[i][j], 0, 0, 0);
    }

    #pragma unroll
    for (int i = 0; i < 2; i++) {
        #pragma unroll
        for (int reg = 0; reg < 4; reg++) {
            int gr = r0 + wm * 32 + i * 16 + quad * 4 + reg;
            #pragma unroll
            for (int j = 0; j < 2; j++) {
                int c = n0 + wn * 32 + j * 16 + ln15;
                float x = acc[i][j][reg] + bias[c];
                float g = 0.5f * x * (1.f + erff(x * 0.70710678118f));
                out[(size_t)gr * DIM + c] = g + feat[(size_t)gr * DIM + c];
            }
        }
    }
}

extern "C" void kernel_launch(void* const* d_in, const int* in_sizes, int n_in,
                              void* d_out, int out_size, void* d_ws, size_t ws_size,
                              hipStream_t stream)
{
    const float* xyzs  = (const float*)d_in[0];
    const float* feat  = (const float*)d_in[1];
    const float* gamma = (const float*)d_in[2];
    const float* beta  = (const float*)d_in[3];
    const float* wqkv  = (const float*)d_in[4];
    const float* wsp   = (const float*)d_in[5];
    const float* wout  = (const float*)d_in[6];
    const float* bout  = (const float*)d_in[7];
    float* out = (float*)d_out;

    unsigned short* ws16 = (unsigned short*)d_ws;
    const size_t SEGS = (size_t)ROWS * DIM;              // 2,097,152 shorts (4 MB)
    unsigned short* normed = ws16;                       // reused as attn_out
    unsigned short* qb     = ws16 + SEGS;
    unsigned short* kb     = ws16 + 2 * SEGS;
    unsigned short* vb     = ws16 + 3 * SEGS;
    unsigned short* wqkvT  = ws16 + 4 * SEGS;            // 786,432 shorts
    unsigned short* woutT  = wqkvT + (size_t)NQK * DIM;  // 262,144 shorts
    unsigned short* obuf   = woutT + (size_t)DIM * DIM;  // 2*32768*72 shorts (9 MB)
    float*          lbuf   = (float*)(obuf + (size_t)2 * NROW * 72); // 2*32768 f32
    unsigned short* xyzT   = (unsigned short*)(lbuf + 2 * NROW);     // 2*3*2048

    pre_kernel<<<ROWS + 257, 256, 0, stream>>>(feat, gamma, beta, normed,
                                               wqkv, wout, wqkvT, woutT,
                                               xyzs, xyzT);
    qkv_gemm<<<dim3(32, 12), 256, 0, stream>>>(normed, wqkvT, qb, kb, vb);
    attn_kernel<<<dim3(32, 16, 2), 256, 0, stream>>>(qb, kb, vb, xyzT, obuf, lbuf);
    merge_kernel<<<512, 256, 0, stream>>>(obuf, lbuf, xyzs, wsp, normed);
    out_gemm<<<dim3(64, 8), 256, 0, stream>>>(normed, woutT, bout, feat, out);
}

// Round 12
// 157.064 us; speedup vs baseline: 1.5451x; 1.5451x over previous
//
#include <hip/hip_runtime.h>
#include <hip/hip_bf16.h>
#include <math.h>

#define BB   2
#define MM   2048      // l*n
#define DIM  512
#define NH   8
#define DHd  64
#define NQK  1536
#define ROWS 4096      // BB*MM
#define NROW 32768     // 16 bh * 2048 rows

typedef __hip_bfloat16 bf16;
typedef __attribute__((ext_vector_type(8))) short bf16x8;
typedef __attribute__((ext_vector_type(4))) float f32x4;
typedef __attribute__((ext_vector_type(8))) unsigned short us8;

__device__ __forceinline__ unsigned short f2bf_bits(float x) {
    bf16 h = __float2bfloat16(x);
    return *(unsigned short*)&h;
}
__device__ __forceinline__ float bf2f(unsigned short u) {
    unsigned int v = ((unsigned int)u) << 16;
    return __uint_as_float(v);
}

// ---- fused pre-pass: LayerNorm (blocks 0..4095) + weight transposes -------
__global__ __launch_bounds__(256) void pre_kernel(
    const float* __restrict__ feat, const float* __restrict__ gamma,
    const float* __restrict__ beta, unsigned short* __restrict__ normed,
    const float* __restrict__ wqkv, const float* __restrict__ wout,
    unsigned short* __restrict__ wqkvT, unsigned short* __restrict__ woutT)
{
    __shared__ float st[64][65];
    int b = blockIdx.x;
    int tid = threadIdx.x;
    if (b < ROWS) {
        const float* fr = feat + (size_t)b * DIM;
        float x0 = fr[tid];
        float x1 = fr[tid + 256];
        float s  = x0 + x1;
        float ss = x0 * x0 + x1 * x1;
        #pragma unroll
        for (int o = 32; o >= 1; o >>= 1) { s += __shfl_down(s, o); ss += __shfl_down(ss, o); }
        __shared__ float ws_[4], wss_[4];
        int wid = tid >> 6, lane = tid & 63;
        if (lane == 0) { ws_[wid] = s; wss_[wid] = ss; }
        __syncthreads();
        if (tid == 0) {
            float a = 0.f, c = 0.f;
            for (int i = 0; i < 4; i++) { a += ws_[i]; c += wss_[i]; }
            ws_[0] = a; wss_[0] = c;
        }
        __syncthreads();
        float mu  = ws_[0] * (1.0f / DIM);
        float var = wss_[0] * (1.0f / DIM) - mu * mu;
        float inv = rsqrtf(var + 1e-5f);
        normed[(size_t)b * DIM + tid]       = f2bf_bits((x0 - mu) * inv * gamma[tid] + beta[tid]);
        normed[(size_t)b * DIM + tid + 256] = f2bf_bits((x1 - mu) * inv * gamma[tid + 256] + beta[tid + 256]);
        return;
    }
    int idx = b - ROWS;
    const float* in; unsigned short* out; int N, n0;
    if (idx < 192) { in = wqkv; out = wqkvT; N = NQK; n0 = (idx >> 3) * 64; }
    else { idx -= 192; in = wout; out = woutT; N = DIM; n0 = (idx >> 3) * 64; }
    int k0 = (idx & 7) * 64;
    #pragma unroll
    for (int p = 0; p < 16; p++) {
        int e = tid + p * 256;
        int r = e >> 6, c = e & 63;
        st[r][c] = in[(size_t)(k0 + r) * N + n0 + c];
    }
    __syncthreads();
    #pragma unroll
    for (int p = 0; p < 16; p++) {
        int e = tid + p * 256;
        int nr = e >> 6, kc = e & 63;
        out[(size_t)(n0 + nr) * DIM + k0 + kc] = f2bf_bits(st[kc][nr]);
    }
}

// ---- QKV GEMM (MFMA): q/k blocks computed transposed (A=weights) so the
//      accumulator's reg axis lands on d -> ushort4 stores. q scaled by
//      (1/8)*log2(e) so attention can use exp2.
__global__ __launch_bounds__(256) void qkv_gemm(
    const unsigned short* __restrict__ A, const unsigned short* __restrict__ BT,
    unsigned short* __restrict__ qd, unsigned short* __restrict__ kd,
    unsigned short* __restrict__ vd)
{
    __shared__ __align__(16) unsigned short sA[128 * 40];
    __shared__ __align__(16) unsigned short sB[128 * 40];
    int tid = threadIdx.x;
    int r0 = blockIdx.x * 128;
    int n0 = blockIdx.y * 128;
    int chunk = n0 >> 9;           // 0=q 1=k 2=v
    int cl    = n0 & 511;
    int w = tid >> 6, lane = tid & 63;
    int wm = w >> 1, wn = w & 1;
    int ln15 = lane & 15, quad = lane >> 4;

    int srow = tid >> 1;
    int scol = (tid & 1) * 16;

    f32x4 acc[4][4] = {};

    for (int k0 = 0; k0 < DIM; k0 += 32) {
        __syncthreads();
        *(us8*)&sA[srow * 40 + scol]     = *(const us8*)&A[(size_t)(r0 + srow) * DIM + k0 + scol];
        *(us8*)&sA[srow * 40 + scol + 8] = *(const us8*)&A[(size_t)(r0 + srow) * DIM + k0 + scol + 8];
        *(us8*)&sB[srow * 40 + scol]     = *(const us8*)&BT[(size_t)(n0 + srow) * DIM + k0 + scol];
        *(us8*)&sB[srow * 40 + scol + 8] = *(const us8*)&BT[(size_t)(n0 + srow) * DIM + k0 + scol + 8];
        __syncthreads();
        const unsigned short* fa = (chunk == 2) ? sA : sB;
        const unsigned short* fb = (chunk == 2) ? sB : sA;
        bf16x8 af[4], bf_[4];
        #pragma unroll
        for (int i = 0; i < 4; i++)
            af[i] = *(const bf16x8*)&fa[(wm * 64 + i * 16 + ln15) * 40 + quad * 8];
        #pragma unroll
        for (int j = 0; j < 4; j++)
            bf_[j] = *(const bf16x8*)&fb[(wn * 64 + j * 16 + ln15) * 40 + quad * 8];
        #pragma unroll
        for (int i = 0; i < 4; i++)
            #pragma unroll
            for (int j = 0; j < 4; j++)
                acc[i][j] = __builtin_amdgcn_mfma_f32_16x16x32_bf16(af[i], bf_[j], acc[i][j], 0, 0, 0);
    }

    if (chunk == 2) {
        int rowb = r0 + wm * 64 + quad * 4;
        #pragma unroll
        for (int j = 0; j < 4; j++) {
            int c = cl + wn * 64 + j * 16 + ln15;
            int h = c >> 6, d = c & 63;
            #pragma unroll
            for (int i = 0; i < 4; i++) {
                int gr = rowb + i * 16;
                int bb = gr >> 11, mm = gr & 2047;
                ushort4 pk;
                pk.x = f2bf_bits(acc[i][j][0]);
                pk.y = f2bf_bits(acc[i][j][1]);
                pk.z = f2bf_bits(acc[i][j][2]);
                pk.w = f2bf_bits(acc[i][j][3]);
                *(ushort4*)&vd[((size_t)(bb * NH + h) * DHd + d) * MM + mm] = pk;
            }
        }
    } else {
        unsigned short* dst = (chunk == 0) ? qd : kd;
        float sc = (chunk == 0) ? 0.125f * 1.44269504f : 1.0f;
        #pragma unroll
        for (int i = 0; i < 4; i++) {
            int within0 = cl + wm * 64 + i * 16 + quad * 4;
            int h = within0 >> 6, d = within0 & 63;
            #pragma unroll
            for (int j = 0; j < 4; j++) {
                int gr = r0 + wn * 64 + j * 16 + ln15;
                int bb = gr >> 11, mm = gr & 2047;
                ushort4 pk;
                pk.x = f2bf_bits(acc[i][j][0] * sc);
                pk.y = f2bf_bits(acc[i][j][1] * sc);
                pk.z = f2bf_bits(acc[i][j][2] * sc);
                pk.w = f2bf_bits(acc[i][j][3] * sc);
                *(ushort4*)&dst[((size_t)(bb * NH + h) * MM + mm) * DHd + d] = pk;
            }
        }
    }
}

// ---------------- MFMA flash attention, split-K(2), LDS-staged (r9 form) ---
// No online max (S bounded); P = exp2(S) with log2e folded into q upstream.
// V extended: cols 64..66 = key xyz, col 67 = 1 (gives l), 68..79 = 0.
__global__ __launch_bounds__(256) void attn_kernel(
    const unsigned short* __restrict__ qg, const unsigned short* __restrict__ kg,
    const unsigned short* __restrict__ vg, const float* __restrict__ xyzs,
    unsigned short* __restrict__ obuf, float* __restrict__ lbuf)
{
    __shared__ __align__(16) unsigned short sQ[64 * 72];
    __shared__ __align__(16) unsigned short sK[64 * 72];
    __shared__ __align__(16) unsigned short sVT[80 * 72];
    __shared__ __align__(16) unsigned short sP[64 * 72];

    int tid = threadIdx.x;
    int bh = blockIdx.y; int bb = bh >> 3;
    int i0 = blockIdx.x * 64;
    int ks = blockIdx.z;
    int w = tid >> 6;
    int lane = tid & 63;
    int ln15 = lane & 15;
    int quad = lane >> 4;

    // one-time inits: zero pad rows 68..79, ones row 67
    for (int e = tid; e < 12 * 72; e += 256) sVT[68 * 72 + e] = 0;
    if (tid < 64) sVT[67 * 72 + tid] = 0x3F80;   // bf16 1.0

    {   // stage Q (each wave writes exactly its own 16 rows)
        const unsigned short* src = qg + ((size_t)bh * MM + i0) * DHd;
        int row = tid >> 2, col = (tid & 3) * 16;
        *(us8*)&sQ[row * 72 + col]     = *(const us8*)&src[(size_t)tid * 16];
        *(us8*)&sQ[row * 72 + col + 8] = *(const us8*)&src[(size_t)tid * 16 + 8];
    }
    asm volatile("s_waitcnt lgkmcnt(0)" ::: "memory");
    bf16x8 aq0 = *(const bf16x8*)&sQ[(w * 16 + ln15) * 72 + quad * 8];
    bf16x8 aq1 = *(const bf16x8*)&sQ[(w * 16 + ln15) * 72 + 32 + quad * 8];

    f32x4 o[5] = {};   // t=0..3: V cols; t=4: [x,y,z,l] at ln15=0..3

    const unsigned short* kbase = kg + (size_t)bh * MM * DHd;
    const unsigned short* vbase = vg + (size_t)bh * DHd * MM;
    int jbeg = ks * (MM / 2), jend = jbeg + (MM / 2);

    int srow = tid >> 2, scol16 = (tid & 3) * 16;   // staging coords (K and VT)

    us8 rk0, rk1, rv0, rv1;
    float rx = 0.f;
    {   // preload first tile
        const unsigned short* src = kbase + (size_t)jbeg * DHd;
        rk0 = *(const us8*)&src[(size_t)tid * 16];
        rk1 = *(const us8*)&src[(size_t)tid * 16 + 8];
        const unsigned short* vs = vbase + jbeg;
        rv0 = *(const us8*)&vs[(size_t)srow * MM + scol16];
        rv1 = *(const us8*)&vs[(size_t)srow * MM + scol16 + 8];
        if (tid < 192) rx = xyzs[((size_t)bb * MM + jbeg) * 3 + tid];
    }

    int pwb = quad << 4;                       // write-side swizzle for sP
    int swzr = (ln15 >> 2) << 4;               // read-side swizzle
    int pr0 = (quad * 8) ^ swzr;
    int pr1 = (32 + quad * 8) ^ swzr;

    for (int jt = jbeg; jt < jend; jt += 64) {
        __syncthreads();
        // commit prefetched tile to LDS
        *(us8*)&sK[srow * 72 + scol16]      = rk0;
        *(us8*)&sK[srow * 72 + scol16 + 8]  = rk1;
        *(us8*)&sVT[srow * 72 + scol16]     = rv0;
        *(us8*)&sVT[srow * 72 + scol16 + 8] = rv1;
        if (tid < 192) {
            int key = tid / 3, c = tid - key * 3;
            sVT[(64 + c) * 72 + key] = f2bf_bits(rx);
        }
        __syncthreads();
        // issue prefetch for next tile (consumed next iteration)
        int jn = jt + 64;
        if (jn < jend) {
            const unsigned short* src = kbase + (size_t)jn * DHd;
            rk0 = *(const us8*)&src[(size_t)tid * 16];
            rk1 = *(const us8*)&src[(size_t)tid * 16 + 8];
            const unsigned short* vs = vbase + jn;
            rv0 = *(const us8*)&vs[(size_t)srow * MM + scol16];
            rv1 = *(const us8*)&vs[(size_t)srow * MM + scol16 + 8];
            if (tid < 192) rx = xyzs[((size_t)bb * MM + jn) * 3 + tid];
        }

        f32x4 sacc[4];
        #pragma unroll
        for (int t = 0; t < 4; t++) {
            bf16x8 bk0 = *(const bf16x8*)&sK[(t * 16 + ln15) * 72 + quad * 8];
            bf16x8 bk1 = *(const bf16x8*)&sK[(t * 16 + ln15) * 72 + 32 + quad * 8];
            f32x4 z = {};
            z = __builtin_amdgcn_mfma_f32_16x16x32_bf16(aq0, bk0, z, 0, 0, 0);
            z = __builtin_amdgcn_mfma_f32_16x16x32_bf16(aq1, bk1, z, 0, 0, 0);
            sacc[t] = z;
        }

        // P = 2^S, packed bf16, swizzled wave-private write
        #pragma unroll
        for (int t = 0; t < 4; t++) {
            int colb = (t * 16) ^ pwb;
            #pragma unroll
            for (int reg = 0; reg < 4; reg++) {
                float pv = exp2f(sacc[t][reg]);
                sP[(w * 16 + quad * 4 + reg) * 72 + colb + ln15] = f2bf_bits(pv);
            }
        }
        asm volatile("s_waitcnt lgkmcnt(0)" ::: "memory");
        bf16x8 ap0 = *(const bf16x8*)&sP[(w * 16 + ln15) * 72 + pr0];
        bf16x8 ap1 = *(const bf16x8*)&sP[(w * 16 + ln15) * 72 + pr1];
        #pragma unroll
        for (int t = 0; t < 5; t++) {
            bf16x8 bv0 = *(const bf16x8*)&sVT[(t * 16 + ln15) * 72 + quad * 8];
            bf16x8 bv1 = *(const bf16x8*)&sVT[(t * 16 + ln15) * 72 + 32 + quad * 8];
            o[t] = __builtin_amdgcn_mfma_f32_16x16x32_bf16(ap0, bv0, o[t], 0, 0, 0);
            o[t] = __builtin_amdgcn_mfma_f32_16x16x32_bf16(ap1, bv1, o[t], 0, 0, 0);
        }
    }

    // ---- store partials (unnormalized O and l; consumer merges)
    size_t kso = (size_t)ks * NROW;
    #pragma unroll
    for (int reg = 0; reg < 4; reg++) {
        size_t row = (size_t)bh * MM + i0 + w * 16 + quad * 4 + reg;
        unsigned short* orow = obuf + (kso + row) * 72;
        #pragma unroll
        for (int t = 0; t < 4; t++)
            orow[t * 16 + ln15] = f2bf_bits(o[t][reg]);
        if (ln15 < 3)  orow[64 + ln15] = f2bf_bits(o[4][reg]);   // xyz agg
        if (ln15 == 3) lbuf[kso + row] = o[4][reg];              // l (fp32)
    }
}

// ---- out kernel: fused split-K merge + w_sp epilogue + GEMM + bias + GeLU
//      + residual -> fp32.  A-tile is computed on the fly from obuf partials.
__global__ __launch_bounds__(256) void out_kernel(
    const unsigned short* __restrict__ obuf, const float* __restrict__ lbuf,
    const float* __restrict__ xyzs, const float* __restrict__ wsp,
    const unsigned short* __restrict__ BT, const float* __restrict__ bias,
    const float* __restrict__ feat, float* __restrict__ out)
{
    __shared__ __align__(16) unsigned short sA[64 * 40];
    __shared__ __align__(16) unsigned short sB[64 * 40];
    __shared__ float4 sM[64][8];    // per (row, head): invl, gx, gy, gz
    __shared__ float sW[3][64];
    int tid = threadIdx.x;
    int r0 = blockIdx.x * 64, n0 = blockIdx.y * 64;
    int bb = r0 >> 11, mm0 = r0 & 2047;
    int w = tid >> 6, lane = tid & 63;
    int wm = w >> 1, wn = w & 1;
    int ln15 = lane & 15, quad = lane >> 4;
    int srow = tid >> 2, scol = (tid & 3) * 8;

    if (tid < 192) sW[tid >> 6][tid & 63] = wsp[tid];
    // per-(row,head) merge scalars (512 pairs over 256 threads)
    for (int p = tid; p < 512; p += 256) {
        int i = p >> 3, h = p & 7;
        int rh = ((bb * 8 + h) << 11) + mm0 + i;
        float invl = 1.f / (lbuf[rh] + lbuf[NROW + rh]);
        const unsigned short* o1 = obuf + (size_t)rh * 72;
        const unsigned short* o2 = obuf + ((size_t)NROW + rh) * 72;
        size_t xb = ((size_t)bb * MM + mm0 + i) * 3;
        float gx = (bf2f(o1[64]) + bf2f(o2[64])) * invl - xyzs[xb + 0];
        float gy = (bf2f(o1[65]) + bf2f(o2[65])) * invl - xyzs[xb + 1];
        float gz = (bf2f(o1[66]) + bf2f(o2[66])) * invl - xyzs[xb + 2];
        sM[i][h] = make_float4(invl, gx, gy, gz);
    }

    f32x4 acc[2][2] = {};

    for (int k0 = 0; k0 < DIM; k0 += 32) {
        __syncthreads();
        {   // fused-merge A staging: cols k0+scol .. +7 (one head, 8-aligned)
            int c0 = k0 + scol;
            int h = c0 >> 6, dd = c0 & 63;
            float4 m = sM[srow][h];
            int rh = ((bb * 8 + h) << 11) + mm0 + srow;
            us8 p1 = *(const us8*)&obuf[(size_t)rh * 72 + dd];
            us8 p2 = *(const us8*)&obuf[((size_t)NROW + rh) * 72 + dd];
            us8 pk;
            #pragma unroll
            for (int e = 0; e < 8; e++) {
                int d = dd + e;
                float v = (bf2f(p1[e]) + bf2f(p2[e])) * m.x
                        + m.y * sW[0][d] + m.z * sW[1][d] + m.w * sW[2][d];
                pk[e] = f2bf_bits(v);
            }
            *(us8*)&sA[srow * 40 + scol] = pk;
        }
        *(us8*)&sB[srow * 40 + scol] = *(const us8*)&BT[(size_t)(n0 + srow) * DIM + k0 + scol];
        __syncthreads();
        bf16x8 af[2], bf_[2];
        #pragma unroll
        for (int i = 0; i < 2; i++)
            af[i] = *(const bf16x8*)&sA[(wm * 32 + i * 16 + ln15) * 40 + quad * 8];
        #pragma unroll
        for (int j = 0; j < 2; j++)
            bf_[j] = *(const bf16x8*)&sB[(wn * 32 + j * 16 + ln15) * 40 + quad * 8];
        #pragma unroll
        for (int i = 0; i < 2; i++)
            #pragma unroll
            for (int j = 0; j < 2; j++)
                acc[i][j] = __builtin_amdgcn_mfma_f32_16x16x32_bf16(af[i], bf_[j], acc[i][j], 0, 0, 0);
    }

    #pragma unroll
    for (int i = 0; i < 2; i++) {
        #pragma unroll
        for (int reg = 0; reg < 4; reg++) {
            int gr = r0 + wm * 32 + i * 16 + quad * 4 + reg;
            #pragma unroll
            for (int j = 0; j < 2; j++) {
                int c = n0 + wn * 32 + j * 16 + ln15;
                float x = acc[i][j][reg] + bias[c];
                float g = 0.5f * x * (1.f + erff(x * 0.70710678118f));
                out[(size_t)gr * DIM + c] = g + feat[(size_t)gr * DIM + c];
            }
        }
    }
}

extern "C" void kernel_launch(void* const* d_in, const int* in_sizes, int n_in,
                              void* d_out, int out_size, void* d_ws, size_t ws_size,
                              hipStream_t stream)
{
    const float* xyzs  = (const float*)d_in[0];
    const float* feat  = (const float*)d_in[1];
    const float* gamma = (const float*)d_in[2];
    const float* beta  = (const float*)d_in[3];
    const float* wqkv  = (const float*)d_in[4];
    const float* wsp   = (const float*)d_in[5];
    const float* wout  = (const float*)d_in[6];
    const float* bout  = (const float*)d_in[7];
    float* out = (float*)d_out;

    unsigned short* ws16 = (unsigned short*)d_ws;
    const size_t SEGS = (size_t)ROWS * DIM;              // 2,097,152 shorts (4 MB)
    unsigned short* normed = ws16;
    unsigned short* qb     = ws16 + SEGS;
    unsigned short* kb     = ws16 + 2 * SEGS;
    unsigned short* vb     = ws16 + 3 * SEGS;
    unsigned short* wqkvT  = ws16 + 4 * SEGS;            // 786,432 shorts
    unsigned short* woutT  = wqkvT + (size_t)NQK * DIM;  // 262,144 shorts
    unsigned short* obuf   = woutT + (size_t)DIM * DIM;  // 2*32768*72 shorts (9 MB)
    float*          lbuf   = (float*)(obuf + (size_t)2 * NROW * 72); // 2*32768 f32

    pre_kernel<<<ROWS + 256, 256, 0, stream>>>(feat, gamma, beta, normed,
                                               wqkv, wout, wqkvT, woutT);
    qkv_gemm<<<dim3(32, 12), 256, 0, stream>>>(normed, wqkvT, qb, kb, vb);
    attn_kernel<<<dim3(32, 16, 2), 256, 0, stream>>>(qb, kb, vb, xyzs, obuf, lbuf);
    out_kernel<<<dim3(64, 8), 256, 0, stream>>>(obuf, lbuf, xyzs, wsp,
                                                woutT, bout, feat, out);
}